// Round 1
// baseline (184.510 us; speedup 1.0000x reference)
//
#include <hip/hip_runtime.h>
#include <stdint.h>

#define BB 2
#define HH 16
#define SS 2048
#define DKK 64
#define DD 1024
#define TT (BB * SS)  // 4096 tokens

typedef __attribute__((ext_vector_type(8))) short bf16x8;
typedef __attribute__((ext_vector_type(4))) float f32x4;

static __device__ __forceinline__ unsigned short f2bf(float f) {
  union { float f; uint32_t u; } c; c.f = f;
  return (unsigned short)((c.u + 0x7FFFu + ((c.u >> 16) & 1u)) >> 16);
}

static __device__ __forceinline__ f32x4 zero4() {
  f32x4 z; z[0] = 0.f; z[1] = 0.f; z[2] = 0.f; z[3] = 0.f; return z;
}

// XOR swizzle within a 64-col bf16 row: 8 groups of 8 elems (16B each).
// Applied identically on LDS write and read -> bank-spread ds_read_b128.
static __device__ __forceinline__ int swz(int row, int col) {
  return ((((col >> 3) ^ row) & 7) << 3) | (col & 7);
}

// ---------------------------------------------------------------- cvt fp32->bf16
struct CvtArgs {
  const float* src[7];
  unsigned short* dst[7];
  int n4[7];
};

__global__ __launch_bounds__(256) void cvt_all(CvtArgs a) {
  const int id = blockIdx.y;
  const float4* s = (const float4*)a.src[id];
  ushort4* d = (ushort4*)a.dst[id];
  const int n4 = a.n4[id];
  for (int i = blockIdx.x * blockDim.x + threadIdx.x; i < n4;
       i += gridDim.x * blockDim.x) {
    float4 v = s[i];
    ushort4 o;
    o.x = f2bf(v.x); o.y = f2bf(v.y); o.z = f2bf(v.z); o.w = f2bf(v.w);
    d[i] = o;
  }
}

// ---------------------------------------------------------------- GEMM C = A @ W^T + bias
// A: [4096][1024] bf16 (token-major), W: [1024][1024] bf16 (row = out channel)
// mode 0: bf16 out, head layout  [b][h][s][dk]
// mode 1: fp32 out, token layout [t][1024]      (final projection -> d_out)
// mode 2: bf16 out, v-transposed [b][h][dk][s]  (for attention PV staging)
struct GemmJob {
  const unsigned short* A;
  const unsigned short* W;
  const float* bias;
  void* out;
  int mode;
};
struct GemmArgs { GemmJob job[3]; };

__global__ __launch_bounds__(256) void gemm_kernel(GemmArgs args) {
  const GemmJob jb = args.job[blockIdx.z];
  __shared__ __align__(16) unsigned short As[128][64];
  __shared__ __align__(16) unsigned short Bs[128][64];
  const int tid = threadIdx.x;
  const int lane = tid & 63;
  const int wv = tid >> 6;
  const int fr = lane & 15, fq = lane >> 4;
  const int wr = (wv >> 1) * 64, wc = (wv & 1) * 64;
  const int m0 = blockIdx.y * 128, n0 = blockIdx.x * 128;
  const unsigned short* __restrict__ A = jb.A;
  const unsigned short* __restrict__ W = jb.W;

  f32x4 acc[4][4];
#pragma unroll
  for (int i = 0; i < 4; ++i)
#pragma unroll
    for (int j = 0; j < 4; ++j) acc[i][j] = zero4();

  bf16x8 ra[4], rb[4];
#pragma unroll
  for (int i = 0; i < 4; ++i) {
    const int c = tid + 256 * i, row = c >> 3, cc = c & 7;
    ra[i] = *(const bf16x8*)(A + (size_t)(m0 + row) * DD + cc * 8);
    rb[i] = *(const bf16x8*)(W + (size_t)(n0 + row) * DD + cc * 8);
  }

  for (int k0 = 0; k0 < DD; k0 += 64) {
    __syncthreads();
#pragma unroll
    for (int i = 0; i < 4; ++i) {
      const int c = tid + 256 * i, row = c >> 3, cc = c & 7;
      *(bf16x8*)&As[row][swz(row, cc * 8)] = ra[i];
      *(bf16x8*)&Bs[row][swz(row, cc * 8)] = rb[i];
    }
    __syncthreads();
    if (k0 + 64 < DD) {
#pragma unroll
      for (int i = 0; i < 4; ++i) {
        const int c = tid + 256 * i, row = c >> 3, cc = c & 7;
        ra[i] = *(const bf16x8*)(A + (size_t)(m0 + row) * DD + (k0 + 64) + cc * 8);
        rb[i] = *(const bf16x8*)(W + (size_t)(n0 + row) * DD + (k0 + 64) + cc * 8);
      }
    }
#pragma unroll
    for (int kk = 0; kk < 2; ++kk) {
      bf16x8 af[4], bf[4];
#pragma unroll
      for (int i = 0; i < 4; ++i) {
        const int r = wr + i * 16 + fr;
        af[i] = *(const bf16x8*)&As[r][swz(r, kk * 32 + fq * 8)];
      }
#pragma unroll
      for (int j = 0; j < 4; ++j) {
        const int r = wc + j * 16 + fr;
        bf[j] = *(const bf16x8*)&Bs[r][swz(r, kk * 32 + fq * 8)];
      }
#pragma unroll
      for (int i = 0; i < 4; ++i)
#pragma unroll
        for (int j = 0; j < 4; ++j)
          acc[i][j] = __builtin_amdgcn_mfma_f32_16x16x32_bf16(af[i], bf[j],
                                                              acc[i][j], 0, 0, 0);
    }
  }

  // Epilogue. C/D layout: col = lane&15 (fr), row = (lane>>4)*4 + r (fq*4+r).
  const int mode = jb.mode;
  if (mode == 1) {
    float* out = (float*)jb.out;
#pragma unroll
    for (int i = 0; i < 4; ++i)
#pragma unroll
      for (int j = 0; j < 4; ++j) {
        const int col = n0 + wc + j * 16 + fr;
        const float bv = jb.bias[col];
#pragma unroll
        for (int r = 0; r < 4; ++r) {
          const int row = m0 + wr + i * 16 + fq * 4 + r;
          out[(size_t)row * DD + col] = acc[i][j][r] + bv;
        }
      }
  } else if (mode == 0) {
    unsigned short* out = (unsigned short*)jb.out;
#pragma unroll
    for (int i = 0; i < 4; ++i)
#pragma unroll
      for (int j = 0; j < 4; ++j) {
        const int col = n0 + wc + j * 16 + fr;
        const float bv = jb.bias[col];
        const int h = col >> 6, dk = col & 63;
#pragma unroll
        for (int r = 0; r < 4; ++r) {
          const int row = m0 + wr + i * 16 + fq * 4 + r;
          const int b = row >> 11, s = row & (SS - 1);
          out[(((size_t)(b * HH + h)) * SS + s) * DKK + dk] = f2bf(acc[i][j][r] + bv);
        }
      }
  } else {  // mode 2: v transposed [b][h][dk][s]
    unsigned short* out = (unsigned short*)jb.out;
#pragma unroll
    for (int i = 0; i < 4; ++i)
#pragma unroll
      for (int j = 0; j < 4; ++j) {
        const int col = n0 + wc + j * 16 + fr;
        const float bv = jb.bias[col];
        const int h = col >> 6, dk = col & 63;
#pragma unroll
        for (int r = 0; r < 4; ++r) {
          const int row = m0 + wr + i * 16 + fq * 4 + r;
          const int b = row >> 11, s = row & (SS - 1);
          out[(((size_t)(b * HH + h)) * DKK + dk) * SS + s] = f2bf(acc[i][j][r] + bv);
        }
      }
  }
}

// ---------------------------------------------------------------- flash attention
// qh/kh: [bh][s][dk] bf16 ; vt: [bh][dk][s] bf16 ; ao: [t][1024] bf16
// grid: (S/64, B*H); 256 threads = 4 waves; each wave owns 16 q rows.
__global__ __launch_bounds__(256) void attn_kernel(
    const unsigned short* __restrict__ qh, const unsigned short* __restrict__ kh,
    const unsigned short* __restrict__ vt, const int* __restrict__ maskp,
    unsigned short* __restrict__ ao) {
  __shared__ __align__(16) unsigned short Ks[64][64];
  __shared__ __align__(16) unsigned short Vts[64][64];  // [dk][kv_local]
  __shared__ __align__(16) unsigned short Ps[4][16][72];
  __shared__ float msk[64];

  const int tid = threadIdx.x;
  const int lane = tid & 63, wv = tid >> 6;
  const int fr = lane & 15, fq = lane >> 4;
  const int bh = blockIdx.y;
  const int bB = bh >> 4, h = bh & 15;
  const int q0 = blockIdx.x * 64;
  const size_t base = (size_t)bh * SS * DKK;   // qh/kh per-head base
  const size_t vbase = (size_t)bh * DKK * SS;  // vt per-head base

  // Q fragments: A-frag rows = lane&15, k = kk*32 + fq*8 .. +7
  bf16x8 aq[2];
  {
    const int qrow = q0 + wv * 16 + fr;
#pragma unroll
    for (int kk = 0; kk < 2; ++kk)
      aq[kk] = *(const bf16x8*)(qh + base + (size_t)qrow * DKK + kk * 32 + fq * 8);
  }

  float mrun[4], lrun[4];
  f32x4 aco[4];
#pragma unroll
  for (int r = 0; r < 4; ++r) { mrun[r] = -1e30f; lrun[r] = 0.f; }
#pragma unroll
  for (int j = 0; j < 4; ++j) aco[j] = zero4();

  for (int kv0 = 0; kv0 < SS; kv0 += 64) {
    __syncthreads();  // previous tile's LDS reads done
#pragma unroll
    for (int i = 0; i < 2; ++i) {
      const int c = tid + 256 * i, row = c >> 3, cc = c & 7;
      *(bf16x8*)&Ks[row][swz(row, cc * 8)] =
          *(const bf16x8*)(kh + base + (size_t)(kv0 + row) * DKK + cc * 8);
      *(bf16x8*)&Vts[row][swz(row, cc * 8)] =
          *(const bf16x8*)(vt + vbase + (size_t)row * SS + kv0 + cc * 8);
    }
    if (tid < 64) msk[tid] = maskp[bB * SS + kv0 + tid] ? 0.f : -1e30f;
    __syncthreads();

    // QK^T: scores 16x64 per wave. D row = fq*4+r (q row), col = j*16+fr (kv)
    f32x4 sc[4];
#pragma unroll
    for (int j = 0; j < 4; ++j) {
      const int kr = j * 16 + fr;
      bf16x8 b0 = *(const bf16x8*)&Ks[kr][swz(kr, fq * 8)];
      bf16x8 b1 = *(const bf16x8*)&Ks[kr][swz(kr, 32 + fq * 8)];
      f32x4 z = zero4();
      z = __builtin_amdgcn_mfma_f32_16x16x32_bf16(aq[0], b0, z, 0, 0, 0);
      z = __builtin_amdgcn_mfma_f32_16x16x32_bf16(aq[1], b1, z, 0, 0, 0);
      sc[j] = z;
    }
#pragma unroll
    for (int j = 0; j < 4; ++j) {
      const float madd = msk[j * 16 + fr];
#pragma unroll
      for (int r = 0; r < 4; ++r) sc[j][r] = sc[j][r] * 0.125f + madd;
    }

    // online softmax per q row (row group = 16 lanes sharing fq)
#pragma unroll
    for (int r = 0; r < 4; ++r) {
      float rm = fmaxf(fmaxf(sc[0][r], sc[1][r]), fmaxf(sc[2][r], sc[3][r]));
      rm = fmaxf(rm, __shfl_xor(rm, 1));
      rm = fmaxf(rm, __shfl_xor(rm, 2));
      rm = fmaxf(rm, __shfl_xor(rm, 4));
      rm = fmaxf(rm, __shfl_xor(rm, 8));
      const float mn = fmaxf(mrun[r], rm);
      const float scl = __expf(mrun[r] - mn);
      mrun[r] = mn;
      float rs = 0.f;
#pragma unroll
      for (int j = 0; j < 4; ++j) {
        const float p = __expf(sc[j][r] - mn);
        sc[j][r] = p;
        rs += p;
      }
      rs += __shfl_xor(rs, 1);
      rs += __shfl_xor(rs, 2);
      rs += __shfl_xor(rs, 4);
      rs += __shfl_xor(rs, 8);
      lrun[r] = lrun[r] * scl + rs;
#pragma unroll
      for (int j = 0; j < 4; ++j) aco[j][r] *= scl;
    }

    // P -> per-wave LDS (bf16), then re-read as A-fragments
#pragma unroll
    for (int j = 0; j < 4; ++j)
#pragma unroll
      for (int r = 0; r < 4; ++r)
        Ps[wv][fq * 4 + r][j * 16 + fr] = f2bf(sc[j][r]);

    bf16x8 pa0 = *(const bf16x8*)&Ps[wv][fr][fq * 8];
    bf16x8 pa1 = *(const bf16x8*)&Ps[wv][fr][32 + fq * 8];

    // PV: out[m][d] += P[m][kv] * V[kv][d]; B^T rows = vt rows (d), k = kv
#pragma unroll
    for (int j = 0; j < 4; ++j) {
      const int dr = j * 16 + fr;
      bf16x8 v0 = *(const bf16x8*)&Vts[dr][swz(dr, fq * 8)];
      bf16x8 v1 = *(const bf16x8*)&Vts[dr][swz(dr, 32 + fq * 8)];
      aco[j] = __builtin_amdgcn_mfma_f32_16x16x32_bf16(pa0, v0, aco[j], 0, 0, 0);
      aco[j] = __builtin_amdgcn_mfma_f32_16x16x32_bf16(pa1, v1, aco[j], 0, 0, 0);
    }
  }

  // normalize + write ao[token][h*64+d] bf16
#pragma unroll
  for (int j = 0; j < 4; ++j)
#pragma unroll
    for (int r = 0; r < 4; ++r) {
      const int row = q0 + wv * 16 + fq * 4 + r;
      const int d = j * 16 + fr;
      const float v = aco[j][r] / lrun[r];
      ao[((size_t)(bB * SS + row)) * DD + h * DKK + d] = f2bf(v);
    }
}

// ---------------------------------------------------------------- launch
extern "C" void kernel_launch(void* const* d_in, const int* in_sizes, int n_in,
                              void* d_out, int out_size, void* d_ws, size_t ws_size,
                              hipStream_t stream) {
  const float* Q = (const float*)d_in[0];
  const float* K = (const float*)d_in[1];
  const float* V = (const float*)d_in[2];
  const int* mask = (const int*)d_in[3];
  const float* Wq = (const float*)d_in[4];
  const float* bq = (const float*)d_in[5];
  const float* Wk = (const float*)d_in[6];
  const float* bk = (const float*)d_in[7];
  const float* Wv = (const float*)d_in[8];
  const float* bv = (const float*)d_in[9];
  const float* Wo = (const float*)d_in[10];
  const float* bo = (const float*)d_in[11];

  char* ws = (char*)d_ws;
  const size_t SZ_X = (size_t)TT * DD * 2;   // 8 MB (bf16 token-major)
  const size_t SZ_W = (size_t)DD * DD * 2;   // 2 MB
  unsigned short* Qb = (unsigned short*)(ws + 0 * SZ_X);
  unsigned short* Kb = (unsigned short*)(ws + 1 * SZ_X);
  unsigned short* Vb = (unsigned short*)(ws + 2 * SZ_X);
  unsigned short* Wqb = (unsigned short*)(ws + 3 * SZ_X);
  unsigned short* Wkb = (unsigned short*)(ws + 3 * SZ_X + 1 * SZ_W);
  unsigned short* Wvb = (unsigned short*)(ws + 3 * SZ_X + 2 * SZ_W);
  unsigned short* Wob = (unsigned short*)(ws + 3 * SZ_X + 3 * SZ_W);
  unsigned short* qh = (unsigned short*)(ws + 3 * SZ_X + 4 * SZ_W);
  unsigned short* kh = (unsigned short*)(ws + 4 * SZ_X + 4 * SZ_W);
  unsigned short* vt = (unsigned short*)(ws + 5 * SZ_X + 4 * SZ_W);
  unsigned short* ao = (unsigned short*)(ws + 6 * SZ_X + 4 * SZ_W);

  CvtArgs ca;
  ca.src[0] = Q;  ca.dst[0] = Qb;  ca.n4[0] = TT * DD / 4;
  ca.src[1] = K;  ca.dst[1] = Kb;  ca.n4[1] = TT * DD / 4;
  ca.src[2] = V;  ca.dst[2] = Vb;  ca.n4[2] = TT * DD / 4;
  ca.src[3] = Wq; ca.dst[3] = Wqb; ca.n4[3] = DD * DD / 4;
  ca.src[4] = Wk; ca.dst[4] = Wkb; ca.n4[4] = DD * DD / 4;
  ca.src[5] = Wv; ca.dst[5] = Wvb; ca.n4[5] = DD * DD / 4;
  ca.src[6] = Wo; ca.dst[6] = Wob; ca.n4[6] = DD * DD / 4;
  cvt_all<<<dim3(1024, 7), 256, 0, stream>>>(ca);

  GemmArgs ga;
  ga.job[0] = {Qb, Wqb, bq, qh, 0};
  ga.job[1] = {Kb, Wkb, bk, kh, 0};
  ga.job[2] = {Vb, Wvb, bv, vt, 2};
  gemm_kernel<<<dim3(DD / 128, TT / 128, 3), 256, 0, stream>>>(ga);

  attn_kernel<<<dim3(SS / 64, BB * HH), 256, 0, stream>>>(qh, kh, vt, mask, ao);

  GemmArgs gf;
  gf.job[0] = {ao, Wob, bo, d_out, 1};
  gf.job[1] = gf.job[0];
  gf.job[2] = gf.job[0];
  gemm_kernel<<<dim3(DD / 128, TT / 128, 1), 256, 0, stream>>>(gf);
}

// Round 2
// 148.013 us; speedup vs baseline: 1.2466x; 1.2466x over previous
//
#include <hip/hip_runtime.h>
#include <stdint.h>

#define BB 2
#define HH 16
#define SS 2048
#define DKK 64
#define DD 1024
#define TT (BB * SS)  // 4096 tokens

typedef __attribute__((ext_vector_type(8))) short bf16x8;
typedef __attribute__((ext_vector_type(4))) float f32x4;

static __device__ __forceinline__ unsigned short f2bf(float f) {
  union { float f; uint32_t u; } c; c.f = f;
  return (unsigned short)((c.u + 0x7FFFu + ((c.u >> 16) & 1u)) >> 16);
}

static __device__ __forceinline__ f32x4 zero4() {
  f32x4 z; z[0] = 0.f; z[1] = 0.f; z[2] = 0.f; z[3] = 0.f; return z;
}

// pack two f32 -> one u32 holding 2 bf16 (lo at low 16 = lower address)
static __device__ __forceinline__ uint32_t cvt_pk_bf16(float lo, float hi) {
  uint32_t r;
  asm("v_cvt_pk_bf16_f32 %0, %1, %2" : "=v"(r) : "v"(lo), "v"(hi));
  return r;
}

// XOR swizzle within a 64-col bf16 row (element-index form).
static __device__ __forceinline__ int swz(int row, int col) {
  return ((((col >> 3) ^ row) & 7) << 3) | (col & 7);
}
// Same swizzle in byte form for a 128-byte row.
static __device__ __forceinline__ int swzB(int row, int byteoff) {
  return (byteoff & 15) | ((((byteoff >> 4) ^ row) & 7) << 4);
}

// ---------------------------------------------------------------- cvt fp32->bf16
struct CvtArgs {
  const float* src[7];
  unsigned short* dst[7];
  int n4[7];
};

__global__ __launch_bounds__(256) void cvt_all(CvtArgs a) {
  const int id = blockIdx.y;
  const float4* s = (const float4*)a.src[id];
  ushort4* d = (ushort4*)a.dst[id];
  const int n4 = a.n4[id];
  for (int i = blockIdx.x * blockDim.x + threadIdx.x; i < n4;
       i += gridDim.x * blockDim.x) {
    float4 v = s[i];
    ushort4 o;
    o.x = f2bf(v.x); o.y = f2bf(v.y); o.z = f2bf(v.z); o.w = f2bf(v.w);
    d[i] = o;
  }
}

// ---------------------------------------------------------------- GEMM C = (A @ W^T + bias) * scale
// A: [4096][1024] bf16 (token-major), W: [1024][1024] bf16 (row = out channel)
// mode 0: bf16 out, head layout  [b][h][s][dk]
// mode 1: fp32 out, token layout [t][1024]      (final projection -> d_out)
// mode 2: bf16 out, v-transposed [b][h][dk][s]  (for attention PV staging)
struct GemmJob {
  const unsigned short* A;
  const unsigned short* W;
  const float* bias;
  void* out;
  int mode;
  float scale;
};
struct GemmArgs { GemmJob job[3]; };

__global__ __launch_bounds__(256) void gemm_kernel(GemmArgs args) {
  const GemmJob jb = args.job[blockIdx.z];
  __shared__ __align__(16) unsigned short As[128][64];
  __shared__ __align__(16) unsigned short Bs[128][64];
  const int tid = threadIdx.x;
  const int lane = tid & 63;
  const int wv = tid >> 6;
  const int fr = lane & 15, fq = lane >> 4;
  const int wr = (wv >> 1) * 64, wc = (wv & 1) * 64;
  const int m0 = blockIdx.y * 128, n0 = blockIdx.x * 128;
  const unsigned short* __restrict__ A = jb.A;
  const unsigned short* __restrict__ W = jb.W;

  f32x4 acc[4][4];
#pragma unroll
  for (int i = 0; i < 4; ++i)
#pragma unroll
    for (int j = 0; j < 4; ++j) acc[i][j] = zero4();

  bf16x8 ra[4], rb[4];
#pragma unroll
  for (int i = 0; i < 4; ++i) {
    const int c = tid + 256 * i, row = c >> 3, cc = c & 7;
    ra[i] = *(const bf16x8*)(A + (size_t)(m0 + row) * DD + cc * 8);
    rb[i] = *(const bf16x8*)(W + (size_t)(n0 + row) * DD + cc * 8);
  }

  for (int k0 = 0; k0 < DD; k0 += 64) {
    __syncthreads();
#pragma unroll
    for (int i = 0; i < 4; ++i) {
      const int c = tid + 256 * i, row = c >> 3, cc = c & 7;
      *(bf16x8*)&As[row][swz(row, cc * 8)] = ra[i];
      *(bf16x8*)&Bs[row][swz(row, cc * 8)] = rb[i];
    }
    __syncthreads();
    if (k0 + 64 < DD) {
#pragma unroll
      for (int i = 0; i < 4; ++i) {
        const int c = tid + 256 * i, row = c >> 3, cc = c & 7;
        ra[i] = *(const bf16x8*)(A + (size_t)(m0 + row) * DD + (k0 + 64) + cc * 8);
        rb[i] = *(const bf16x8*)(W + (size_t)(n0 + row) * DD + (k0 + 64) + cc * 8);
      }
    }
#pragma unroll
    for (int kk = 0; kk < 2; ++kk) {
      bf16x8 af[4], bfr[4];
#pragma unroll
      for (int i = 0; i < 4; ++i) {
        const int r = wr + i * 16 + fr;
        af[i] = *(const bf16x8*)&As[r][swz(r, kk * 32 + fq * 8)];
      }
#pragma unroll
      for (int j = 0; j < 4; ++j) {
        const int r = wc + j * 16 + fr;
        bfr[j] = *(const bf16x8*)&Bs[r][swz(r, kk * 32 + fq * 8)];
      }
#pragma unroll
      for (int i = 0; i < 4; ++i)
#pragma unroll
        for (int j = 0; j < 4; ++j)
          acc[i][j] = __builtin_amdgcn_mfma_f32_16x16x32_bf16(af[i], bfr[j],
                                                              acc[i][j], 0, 0, 0);
    }
  }

  // Epilogue. C/D layout: col = lane&15 (fr), row = (lane>>4)*4 + r (fq*4+r).
  const int mode = jb.mode;
  const float scale = jb.scale;
  if (mode == 1) {
    float* out = (float*)jb.out;
#pragma unroll
    for (int i = 0; i < 4; ++i)
#pragma unroll
      for (int j = 0; j < 4; ++j) {
        const int col = n0 + wc + j * 16 + fr;
        const float bv = jb.bias[col];
#pragma unroll
        for (int r = 0; r < 4; ++r) {
          const int row = m0 + wr + i * 16 + fq * 4 + r;
          out[(size_t)row * DD + col] = (acc[i][j][r] + bv) * scale;
        }
      }
  } else if (mode == 0) {
    unsigned short* out = (unsigned short*)jb.out;
#pragma unroll
    for (int i = 0; i < 4; ++i)
#pragma unroll
      for (int j = 0; j < 4; ++j) {
        const int col = n0 + wc + j * 16 + fr;
        const float bv = jb.bias[col];
        const int h = col >> 6, dk = col & 63;
#pragma unroll
        for (int r = 0; r < 4; ++r) {
          const int row = m0 + wr + i * 16 + fq * 4 + r;
          const int b = row >> 11, s = row & (SS - 1);
          out[(((size_t)(b * HH + h)) * SS + s) * DKK + dk] =
              f2bf((acc[i][j][r] + bv) * scale);
        }
      }
  } else {  // mode 2: v transposed [b][h][dk][s]
    unsigned short* out = (unsigned short*)jb.out;
#pragma unroll
    for (int i = 0; i < 4; ++i)
#pragma unroll
      for (int j = 0; j < 4; ++j) {
        const int col = n0 + wc + j * 16 + fr;
        const float bv = jb.bias[col];
        const int h = col >> 6, dk = col & 63;
#pragma unroll
        for (int r = 0; r < 4; ++r) {
          const int row = m0 + wr + i * 16 + fq * 4 + r;
          const int b = row >> 11, s = row & (SS - 1);
          out[(((size_t)(b * HH + h)) * DKK + dk) * SS + s] =
              f2bf((acc[i][j][r] + bv) * scale);
        }
      }
  }
}

// ---------------------------------------------------------------- flash attention (swapped-MFMA, lane-local softmax)
// qh: [bh][s][dk] bf16, PRE-SCALED by (1/sqrt(DK))*log2(e)
// kh: [bh][s][dk] bf16 ; vt: [bh][dk][s] bf16 ; ao: [t][1024] bf16
// grid: (S/64, B*H); 256 threads = 4 waves; each wave owns 16 q rows.
// Swapped QK^T: D[kv][q] (col=q=lane&15) -> each lane owns ONE q row.
// Swapped PV:   D[d][q]  (col=q=lane&15) -> m/l/acc all lane-local.
__global__ __launch_bounds__(256) void attn_kernel(
    const unsigned short* __restrict__ qh, const unsigned short* __restrict__ kh,
    const unsigned short* __restrict__ vt, const int* __restrict__ maskp,
    unsigned short* __restrict__ ao) {
  __shared__ __align__(16) unsigned short Ks[64][64];
  __shared__ __align__(16) unsigned short Vts[64][64];  // [dk][kv_local]
  __shared__ __align__(16) unsigned short Ps[4][16][64]; // per-wave P[q][kv], swizzled
  __shared__ __align__(16) float msk[64];

  const int tid = threadIdx.x;
  const int lane = tid & 63, wv = tid >> 6;
  const int fr = lane & 15, fq = lane >> 4;
  const int bh = blockIdx.y;
  const int bB = bh >> 4, h = bh & 15;
  const int q0 = blockIdx.x * 64;
  const size_t base = (size_t)bh * SS * DKK;   // qh/kh per-head base
  const size_t vbase = (size_t)bh * DKK * SS;  // vt per-head base

  // Q as B-fragment: lane holds Q[q = q0+wv*16+fr][k = kk*32 + fq*8 .. +7]
  bf16x8 aq[2];
  {
    const int qrow = q0 + wv * 16 + fr;
#pragma unroll
    for (int kk = 0; kk < 2; ++kk)
      aq[kk] = *(const bf16x8*)(qh + base + (size_t)qrow * DKK + kk * 32 + fq * 8);
  }

  float mrun = -1e30f, lrun = 0.f;
  f32x4 aco[4];  // aco[j][r] = O[q=fr][d = j*16 + fq*4 + r]
#pragma unroll
  for (int j = 0; j < 4; ++j) aco[j] = zero4();

  char* PsW = (char*)&Ps[wv][0][0];

  for (int kv0 = 0; kv0 < SS; kv0 += 64) {
    __syncthreads();  // previous tile's LDS reads done
#pragma unroll
    for (int i = 0; i < 2; ++i) {
      const int c = tid + 256 * i, row = c >> 3, cc = c & 7;
      *(bf16x8*)&Ks[row][swz(row, cc * 8)] =
          *(const bf16x8*)(kh + base + (size_t)(kv0 + row) * DKK + cc * 8);
      *(bf16x8*)&Vts[row][swz(row, cc * 8)] =
          *(const bf16x8*)(vt + vbase + (size_t)row * SS + kv0 + cc * 8);
    }
    if (tid < 64) msk[tid] = maskp[bB * SS + kv0 + tid] ? 0.f : -1e30f;
    __syncthreads();

    // QK^T swapped: sc[j][r] = S^T[kv = j*16+fq*4+r][q = fr]  (log2-domain)
    f32x4 sc[4];
    __builtin_amdgcn_s_setprio(1);
#pragma unroll
    for (int j = 0; j < 4; ++j) {
      const int kr = j * 16 + fr;
      bf16x8 b0 = *(const bf16x8*)&Ks[kr][swz(kr, fq * 8)];
      bf16x8 b1 = *(const bf16x8*)&Ks[kr][swz(kr, 32 + fq * 8)];
      f32x4 z = zero4();
      z = __builtin_amdgcn_mfma_f32_16x16x32_bf16(b0, aq[0], z, 0, 0, 0);
      z = __builtin_amdgcn_mfma_f32_16x16x32_bf16(b1, aq[1], z, 0, 0, 0);
      sc[j] = z;
    }
    __builtin_amdgcn_s_setprio(0);

    // mask add (broadcast float4 reads)
#pragma unroll
    for (int j = 0; j < 4; ++j) {
      const float4 mv = *(const float4*)&msk[j * 16 + fq * 4];
#pragma unroll
      for (int r = 0; r < 4; ++r) sc[j][r] += ((const float*)&mv)[r];
    }

    // lane-local row max (16 values) + 2 shuffles across fq
    float tm = fmaxf(fmaxf(sc[0][0], sc[0][1]), fmaxf(sc[0][2], sc[0][3]));
#pragma unroll
    for (int j = 1; j < 4; ++j)
      tm = fmaxf(tm, fmaxf(fmaxf(sc[j][0], sc[j][1]), fmaxf(sc[j][2], sc[j][3])));
    tm = fmaxf(tm, __shfl_xor(tm, 16));
    tm = fmaxf(tm, __shfl_xor(tm, 32));

    // defer-max: only rescale when max grew by > 8 (log2 domain)
    if (__any(tm - mrun > 8.f)) {
      const float mnew = fmaxf(mrun, tm);
      const float scl = __builtin_amdgcn_exp2f(mrun - mnew);
      lrun *= scl;
#pragma unroll
      for (int j = 0; j < 4; ++j)
#pragma unroll
        for (int r = 0; r < 4; ++r) aco[j][r] *= scl;
      mrun = mnew;
    }

    // P = exp2(sc - m), lane-local sum + 2 shuffles
    float ts = 0.f;
#pragma unroll
    for (int j = 0; j < 4; ++j)
#pragma unroll
      for (int r = 0; r < 4; ++r) {
        const float p = __builtin_amdgcn_exp2f(sc[j][r] - mrun);
        sc[j][r] = p;
        ts += p;
      }
    ts += __shfl_xor(ts, 16);
    ts += __shfl_xor(ts, 32);
    lrun += ts;

    // P -> per-wave LDS: row q=fr, cols kv=j*16+fq*4..+3 (4 contiguous bf16 = 8B)
#pragma unroll
    for (int j = 0; j < 4; ++j) {
      uint2 w;
      w.x = cvt_pk_bf16(sc[j][0], sc[j][1]);
      w.y = cvt_pk_bf16(sc[j][2], sc[j][3]);
      *(uint2*)(PsW + fr * 128 + swzB(fr, j * 32 + fq * 8)) = w;
    }

    // re-read P as B-fragment: lane holds P[q=fr][kv = kk*32 + fq*8 .. +7]
    bf16x8 pa0 = *(const bf16x8*)(PsW + fr * 128 + swzB(fr, fq * 16));
    bf16x8 pa1 = *(const bf16x8*)(PsW + fr * 128 + swzB(fr, 64 + fq * 16));

    // PV swapped: aco[j] += V^T_frag(j) * P^T_frag ; D[d][q], col=q=fr
    __builtin_amdgcn_s_setprio(1);
#pragma unroll
    for (int j = 0; j < 4; ++j) {
      const int dr = j * 16 + fr;
      bf16x8 v0 = *(const bf16x8*)&Vts[dr][swz(dr, fq * 8)];
      bf16x8 v1 = *(const bf16x8*)&Vts[dr][swz(dr, 32 + fq * 8)];
      aco[j] = __builtin_amdgcn_mfma_f32_16x16x32_bf16(v0, pa0, aco[j], 0, 0, 0);
      aco[j] = __builtin_amdgcn_mfma_f32_16x16x32_bf16(v1, pa1, aco[j], 0, 0, 0);
    }
    __builtin_amdgcn_s_setprio(0);
  }

  // normalize + write ao[token][h*64+d] bf16; d = j*16+fq*4+r (4 contiguous)
  const float inv = 1.f / lrun;
  const int token = bB * SS + q0 + wv * 16 + fr;
#pragma unroll
  for (int j = 0; j < 4; ++j) {
    ushort4 o;
    o.x = f2bf(aco[j][0] * inv);
    o.y = f2bf(aco[j][1] * inv);
    o.z = f2bf(aco[j][2] * inv);
    o.w = f2bf(aco[j][3] * inv);
    *(ushort4*)&ao[(size_t)token * DD + h * DKK + j * 16 + fq * 4] = o;
  }
}

// ---------------------------------------------------------------- launch
extern "C" void kernel_launch(void* const* d_in, const int* in_sizes, int n_in,
                              void* d_out, int out_size, void* d_ws, size_t ws_size,
                              hipStream_t stream) {
  const float* Q = (const float*)d_in[0];
  const float* K = (const float*)d_in[1];
  const float* V = (const float*)d_in[2];
  const int* mask = (const int*)d_in[3];
  const float* Wq = (const float*)d_in[4];
  const float* bq = (const float*)d_in[5];
  const float* Wk = (const float*)d_in[6];
  const float* bk = (const float*)d_in[7];
  const float* Wv = (const float*)d_in[8];
  const float* bv = (const float*)d_in[9];
  const float* Wo = (const float*)d_in[10];
  const float* bo = (const float*)d_in[11];

  char* ws = (char*)d_ws;
  const size_t SZ_X = (size_t)TT * DD * 2;   // 8 MB (bf16 token-major)
  const size_t SZ_W = (size_t)DD * DD * 2;   // 2 MB
  unsigned short* Qb = (unsigned short*)(ws + 0 * SZ_X);
  unsigned short* Kb = (unsigned short*)(ws + 1 * SZ_X);
  unsigned short* Vb = (unsigned short*)(ws + 2 * SZ_X);
  unsigned short* Wqb = (unsigned short*)(ws + 3 * SZ_X);
  unsigned short* Wkb = (unsigned short*)(ws + 3 * SZ_X + 1 * SZ_W);
  unsigned short* Wvb = (unsigned short*)(ws + 3 * SZ_X + 2 * SZ_W);
  unsigned short* Wob = (unsigned short*)(ws + 3 * SZ_X + 3 * SZ_W);
  unsigned short* qh = (unsigned short*)(ws + 3 * SZ_X + 4 * SZ_W);
  unsigned short* kh = (unsigned short*)(ws + 4 * SZ_X + 4 * SZ_W);
  unsigned short* vt = (unsigned short*)(ws + 5 * SZ_X + 4 * SZ_W);
  unsigned short* ao = (unsigned short*)(ws + 6 * SZ_X + 4 * SZ_W);

  CvtArgs ca;
  ca.src[0] = Q;  ca.dst[0] = Qb;  ca.n4[0] = TT * DD / 4;
  ca.src[1] = K;  ca.dst[1] = Kb;  ca.n4[1] = TT * DD / 4;
  ca.src[2] = V;  ca.dst[2] = Vb;  ca.n4[2] = TT * DD / 4;
  ca.src[3] = Wq; ca.dst[3] = Wqb; ca.n4[3] = DD * DD / 4;
  ca.src[4] = Wk; ca.dst[4] = Wkb; ca.n4[4] = DD * DD / 4;
  ca.src[5] = Wv; ca.dst[5] = Wvb; ca.n4[5] = DD * DD / 4;
  ca.src[6] = Wo; ca.dst[6] = Wob; ca.n4[6] = DD * DD / 4;
  cvt_all<<<dim3(1024, 7), 256, 0, stream>>>(ca);

  // Q pre-scaled by (1/sqrt(64)) * log2(e) so attention works in exp2 domain.
  const float SCALE_Q = 0.125f * 1.44269504088896f;

  GemmArgs ga;
  ga.job[0] = {Qb, Wqb, bq, qh, 0, SCALE_Q};
  ga.job[1] = {Kb, Wkb, bk, kh, 0, 1.0f};
  ga.job[2] = {Vb, Wvb, bv, vt, 2, 1.0f};
  gemm_kernel<<<dim3(DD / 128, TT / 128, 3), 256, 0, stream>>>(ga);

  attn_kernel<<<dim3(SS / 64, BB * HH), 256, 0, stream>>>(qh, kh, vt, mask, ao);

  GemmArgs gf;
  gf.job[0] = {ao, Wob, bo, d_out, 1, 1.0f};
  gf.job[1] = gf.job[0];
  gf.job[2] = gf.job[0];
  gemm_kernel<<<dim3(DD / 128, TT / 128, 1), 256, 0, stream>>>(gf);
}